// Round 6
// baseline (803.324 us; speedup 1.0000x reference)
//
#include <hip/hip_runtime.h>
#include <math.h>

// B=4, S=4096 -> 16384 tokens; H=4096; E=64; TOP_K=2
#define TOKENS 16384
#define HDIM 4096
#define NE 64

#define TPW 16                  // tokens per wave
#define KSPLIT 8                // K slices
#define KSLICE (HDIM / KSPLIT)  // 512

// GEMM, LDS-free: lane = expert (E == wavefront == 64).
// Rounds 1-5 all hit the LDS pipe ceiling (~85 B/cyc/CU for ds_read_b128):
// 1 B/MAC staged through LDS = 82+ us floor, measured 170 us w/ VALUBusy 36%.
// Here: A is wave-uniform -> scalar path (s_load -> SGPR -> v_fma src0),
// W is lane-varying -> VGPRs (each 64B line read once, W re-read = 1 GiB L2).
// Zero LDS, zero barriers; inner loop is pure FMA + co-issued loads.
__global__ __launch_bounds__(256) void router_gemm(const float* __restrict__ A,
                                                   const float* __restrict__ W,
                                                   float* __restrict__ P) {
  const int lane = threadIdx.x & 63;
  // readfirstlane: LLVM's divergence analysis treats tid>>6 as divergent,
  // which would block s_load promotion of everything derived from it.
  const int wave = __builtin_amdgcn_readfirstlane(threadIdx.x >> 6);
  const int tok0 = blockIdx.x * (4 * TPW) + wave * TPW;  // 64 tokens/block
  const int kbeg = blockIdx.y * KSLICE;

  const float* Arow = A + (size_t)tok0 * HDIM + kbeg;  // uniform base
  const float* Wrow = W + (size_t)lane * HDIM + kbeg;  // per-lane expert row

  float acc[TPW];
#pragma unroll
  for (int t = 0; t < TPW; ++t) acc[t] = 0.f;

  for (int kc = 0; kc < KSLICE; kc += 16) {
    float4 w[4];
#pragma unroll
    for (int j = 0; j < 4; ++j) w[j] = *(const float4*)(Wrow + kc + j * 4);
#pragma unroll
    for (int j = 0; j < 4; ++j) {
#pragma unroll
      for (int t = 0; t < TPW; ++t) {
        // uniform address (tok0,t,kc,j only) -> s_load_dwordx4, imm offset
        float4 a = *(const float4*)(Arow + (size_t)t * HDIM + kc + j * 4);
        acc[t] = fmaf(a.x, w[j].x, acc[t]);
        acc[t] = fmaf(a.y, w[j].y, acc[t]);
        acc[t] = fmaf(a.z, w[j].z, acc[t]);
        acc[t] = fmaf(a.w, w[j].w, acc[t]);
      }
    }
  }

  // P[ks][tok][e]: lane-contiguous dword stores, perfectly coalesced
  float* Pb = P + ((size_t)blockIdx.y * TOKENS + tok0) * NE + lane;
#pragma unroll
  for (int t = 0; t < TPW; ++t) Pb[(size_t)t * NE] = acc[t];
}

// Finalize: wave = token, lane = expert. Coalesced partial-sum reads,
// shuffle softmax + top-2 (ballot lowest-index tie-break == np/jax).
__global__ __launch_bounds__(256) void router_finalize(const float* __restrict__ P,
                                                       float* __restrict__ out) {
  const int lane = threadIdx.x & 63;
  const int wave = threadIdx.x >> 6;
  const int tok = blockIdx.x * 4 + wave;

  float l = 0.f;
#pragma unroll
  for (int s = 0; s < KSPLIT; ++s)
    l += P[((size_t)s * TOKENS + tok) * NE + lane];

  float m = l;
#pragma unroll
  for (int off = 32; off >= 1; off >>= 1) m = fmaxf(m, __shfl_xor(m, off, 64));

  const float e = expf(l - m);
  float sum = e;
#pragma unroll
  for (int off = 32; off >= 1; off >>= 1) sum += __shfl_xor(sum, off, 64);

  const float p = e / sum;
  out[(size_t)tok * NE + lane] = p;

  float m0 = p;
#pragma unroll
  for (int off = 32; off >= 1; off >>= 1) m0 = fmaxf(m0, __shfl_xor(m0, off, 64));
  const unsigned long long b0 = __ballot(p == m0);
  const int i0 = __ffsll(b0) - 1;

  const float pm = (lane == i0) ? -1.f : p;
  float m1 = pm;
#pragma unroll
  for (int off = 32; off >= 1; off >>= 1) m1 = fmaxf(m1, __shfl_xor(m1, off, 64));
  const unsigned long long b1 = __ballot(pm == m1);
  const int i1 = __ffsll(b1) - 1;

  if (lane == 0) {
    float* idxo = out + (size_t)TOKENS * NE + (size_t)tok * 2;
    idxo[0] = (float)i0;
    idxo[1] = (float)i1;
    float* wo = out + (size_t)TOKENS * NE + (size_t)TOKENS * 2 + (size_t)tok * 2;
    const float d = m0 + m1;
    wo[0] = m0 / d;
    wo[1] = m1 / d;
  }
}

extern "C" void kernel_launch(void* const* d_in, const int* in_sizes, int n_in,
                              void* d_out, int out_size, void* d_ws, size_t ws_size,
                              hipStream_t stream) {
  const float* A = (const float*)d_in[0];  // hidden_states [16384, 4096] f32
  const float* W = (const float*)d_in[1];  // gate_weight   [64, 4096] f32
  float* out = (float*)d_out;
  float* P = (float*)d_ws;                 // 8*16384*64*4 = 32 MiB partials

  dim3 gridA(TOKENS / (4 * TPW), KSPLIT);  // 256 x 8 = 2048 blocks, 256 thr
  router_gemm<<<gridA, 256, 0, stream>>>(A, W, P);
  router_finalize<<<TOKENS / 4, 256, 0, stream>>>(P, out);
}